// Round 3
// baseline (213.005 us; speedup 1.0000x reference)
//
#include <hip/hip_runtime.h>
#include <cstdint>
#include <cstddef>

#define MB_   4096
#define NK_   8
#define DM_   1024
#define DT_   128

typedef __bf16 bf16;
typedef __bf16 bf16x8 __attribute__((ext_vector_type(8)));
typedef __bf16 bf16x4 __attribute__((ext_vector_type(4)));
typedef float  f32x4  __attribute__((ext_vector_type(4)));

__device__ __forceinline__ void gload_lds16(const void* g, void* l) {
  __builtin_amdgcn_global_load_lds(
      (__attribute__((address_space(1))) void*)g,
      (__attribute__((address_space(3))) void*)l,
      16, 0, 0);
}

// XOR swizzle: logical 16B-chunk c of row r lives at LDS slot c ^ hsw(r).
__device__ __forceinline__ int hsw(int r) { return (r ^ (r >> 2)) & 3; }

// ---------------------------------------------------------------------------
// prep: proj_w f32 [8192][1024] -> bf16
__global__ void prep_pw_kernel(const float* __restrict__ pw, bf16* __restrict__ pwb) {
  size_t i = ((size_t)blockIdx.x * 256 + threadIdx.x) * 4;
  float4 f = *(const float4*)&pw[i];
  bf16x4 o = { (bf16)f.x, (bf16)f.y, (bf16)f.z, (bf16)f.w };
  *(bf16x4*)&pwb[i] = o;
}

// prep: w_vs [8][1024][128] f32 -> WvT [8][128][1024] bf16
__global__ void prep_wvt_kernel(const float* __restrict__ wvs, bf16* __restrict__ wvt) {
  int o = blockIdx.x * 256 + threadIdx.x;
  int d = o & 1023;
  int t = (o >> 10) & 127;
  int n = o >> 17;
  wvt[o] = (bf16)wvs[(size_t)n * 131072 + (size_t)d * 128 + t];
}

__global__ void fill_attns_kernel(float* __restrict__ out) {
  out[(size_t)33554432 + blockIdx.x * 256 + threadIdx.x] = 1.0f;
}

// ---------------------------------------------------------------------------
// GEMM1: v_s[n] = V_n[4096x1024](f32) @ WvT[n][128x1024]^T -> A2 scatter (bf16)
__global__ __launch_bounds__(256, 2) void gemm1_kernel(
    const float* __restrict__ vflat, const bf16* __restrict__ WvT,
    bf16* __restrict__ A2)
{
  __shared__ __align__(16) bf16 As[64 * 32];
  __shared__ __align__(16) bf16 Bs[128 * 32];
  const int tid  = threadIdx.x;
  const int wave = tid >> 6, lane = tid & 63;
  const int wm = wave >> 1, wn = wave & 1;
  const int n  = blockIdx.y;
  const int b0 = blockIdx.x * 64;

  const int r  = tid >> 2;
  const int hr = hsw(r);
  const int cs = (tid & 3) ^ hr;

  const float* ag = vflat + ((size_t)(n * MB_ + b0 + r)) * 1024 + (tid & 3) * 8;
  bf16* awr = As + r * 32 + cs * 8;
  const bf16* bg = WvT + (size_t)n * 131072 + (size_t)r * 1024 + cs * 8;
  char* bsb = (char*)Bs + wave * 1024;

  f32x4 acc[2][4] = {};
  const int krow = lane & 15;
  const int cch  = lane >> 4;
  const int swoff = ((cch ^ hsw(krow)) << 4);

  for (int kt = 0; kt < 32; ++kt) {
    const bf16* bptr = bg + kt * 32;
    gload_lds16(bptr,             bsb);
    gload_lds16(bptr + 64 * 1024, bsb + 4096);
    const float* aptr = ag + kt * 32;
    float4 f0 = *(const float4*)(aptr + 0);
    float4 f1 = *(const float4*)(aptr + 4);
    bf16x8 h0 = { (bf16)f0.x, (bf16)f0.y, (bf16)f0.z, (bf16)f0.w,
                  (bf16)f1.x, (bf16)f1.y, (bf16)f1.z, (bf16)f1.w };
    *(bf16x8*)awr = h0;
    __syncthreads();

    bf16x8 af[2], bfr[4];
    #pragma unroll
    for (int i = 0; i < 2; ++i)
      af[i] = *(const bf16x8*)((const char*)As + (wm * 32 + i * 16 + krow) * 64 + swoff);
    #pragma unroll
    for (int j = 0; j < 4; ++j)
      bfr[j] = *(const bf16x8*)((const char*)Bs + (wn * 64 + j * 16 + krow) * 64 + swoff);
    #pragma unroll
    for (int i = 0; i < 2; ++i)
      #pragma unroll
      for (int j = 0; j < 4; ++j)
        acc[i][j] = __builtin_amdgcn_mfma_f32_16x16x32_bf16(af[i], bfr[j], acc[i][j], 0, 0, 0);
    __syncthreads();
  }

  #pragma unroll
  for (int i = 0; i < 2; ++i) {
    #pragma unroll
    for (int j = 0; j < 4; ++j) {
      int t = wn * 64 + j * 16 + (lane & 15);
      #pragma unroll
      for (int rr = 0; rr < 4; ++rr) {
        int b = b0 + wm * 32 + i * 16 + (lane >> 4) * 4 + rr;
        size_t off = ((size_t)(n * 512 + (b >> 3))) * 1024 + (size_t)(b & 7) * 128 + t;
        A2[off] = (bf16)acc[i][j][rr];
      }
    }
  }
}

// ---------------------------------------------------------------------------
// Fused GEMM2 + bias + residual + LayerNorm.
// Block = 64 rows x 1024 cols (one full LN band). 8 waves, wave = 64x128.
// BK=32, double-buffered LDS, 2-phase pipeline. bid&7 = band j (XCD-pinned).
__global__ __launch_bounds__(512, 2) void gemm2ln_kernel(
    const bf16* __restrict__ A2, const bf16* __restrict__ PW,
    const float* __restrict__ vres, const float* __restrict__ pb,
    const float* __restrict__ gamma, const float* __restrict__ beta,
    float* __restrict__ outp)
{
  __shared__ __align__(16) bf16 As[2][64 * 32];
  __shared__ __align__(16) bf16 Bs[2][1024 * 32];
  __shared__ float sred[2][64][8];

  const int tid  = threadIdx.x;
  const int w    = tid >> 6;
  const int lane = tid & 63;

  const int bid = blockIdx.x;      // 0..511
  const int j   = bid & 7;         // dm band -> XCD j
  const int m0  = (bid >> 3) * 64; // row tile
  const int nc0 = j * 1024;

  // A staging: threads 0..255, chunk tid of [64][4] chunks (swizzled source)
  const int ra = tid >> 2;
  const int ca = (tid & 3) ^ hsw(ra);
  const bf16* aSrc = A2 + (size_t)(m0 + ra) * 1024 + ca * 8;
  // B staging: 8 chunks/thread, chunk s = q*512 + tid of [1024][4]
  int bOff[8];
  #pragma unroll
  for (int q = 0; q < 8; ++q) {
    int s  = q * 512 + tid;
    int rb = s >> 2;
    int cb = (s & 3) ^ hsw(rb);
    bOff[q] = (nc0 + rb) * 1024 + cb * 8;
  }

  f32x4 acc[4][8] = {};
  const int krow = lane & 15;
  const int cch  = lane >> 4;
  const int swoff = ((cch ^ hsw(krow)) << 4);

  // prologue: stage K-tile 0 into buf 0
  {
    #pragma unroll
    for (int q = 0; q < 8; ++q)
      gload_lds16(PW + bOff[q], (char*)Bs[0] + q * 8192 + w * 1024);
    if (w < 4) gload_lds16(aSrc, (char*)As[0] + w * 1024);
  }
  __syncthreads();

  for (int t = 0; t < 32; ++t) {
    const int cur = t & 1;
    if (t < 31) {
      const int k0 = (t + 1) * 32;
      #pragma unroll
      for (int q = 0; q < 8; ++q)
        gload_lds16(PW + bOff[q] + k0, (char*)Bs[cur ^ 1] + q * 8192 + w * 1024);
      if (w < 4) gload_lds16(aSrc + k0, (char*)As[cur ^ 1] + w * 1024);
    }
    bf16x8 af[4], bfr[8];
    #pragma unroll
    for (int i = 0; i < 4; ++i)
      af[i] = *(const bf16x8*)((const char*)As[cur] + (i * 16 + krow) * 64 + swoff);
    #pragma unroll
    for (int n = 0; n < 8; ++n)
      bfr[n] = *(const bf16x8*)((const char*)Bs[cur] + (w * 128 + n * 16 + krow) * 64 + swoff);
    #pragma unroll
    for (int i = 0; i < 4; ++i)
      #pragma unroll
      for (int n = 0; n < 8; ++n)
        acc[i][n] = __builtin_amdgcn_mfma_f32_16x16x32_bf16(af[i], bfr[n], acc[i][n], 0, 0, 0);
    __syncthreads();
  }

  // ---- epilogue: x = acc + pb + v; LayerNorm over the 1024-wide band ----
  const int g = lane >> 4, q16 = lane & 15;
  float pbv[8], gav[8], bev[8];
  #pragma unroll
  for (int n = 0; n < 8; ++n) {
    int c = w * 128 + n * 16 + q16;
    pbv[n] = pb[nc0 + c];
    gav[n] = gamma[c];
    bev[n] = beta[c];
  }
  #pragma unroll
  for (int i = 0; i < 4; ++i) {
    #pragma unroll
    for (int r = 0; r < 4; ++r) {
      int row = m0 + i * 16 + g * 4 + r;
      const float* vrow = vres + (size_t)row * 8192 + nc0 + w * 128 + q16;
      #pragma unroll
      for (int n = 0; n < 8; ++n)
        acc[i][n][r] += pbv[n] + vrow[n * 16];
    }
  }
  // per-row sums over this wave's 128 cols (8 frags in regs + 16-lane shfl)
  float sv[16], qv[16];
  #pragma unroll
  for (int i = 0; i < 4; ++i) {
    #pragma unroll
    for (int r = 0; r < 4; ++r) {
      float s = 0.0f, q2 = 0.0f;
      #pragma unroll
      for (int n = 0; n < 8; ++n) { float x = acc[i][n][r]; s += x; q2 += x * x; }
      #pragma unroll
      for (int m = 8; m >= 1; m >>= 1) {
        s  += __shfl_xor(s,  m, 64);
        q2 += __shfl_xor(q2, m, 64);
      }
      sv[i * 4 + r] = s; qv[i * 4 + r] = q2;
    }
  }
  if (q16 == 0) {
    #pragma unroll
    for (int i = 0; i < 4; ++i)
      #pragma unroll
      for (int r = 0; r < 4; ++r) {
        sred[0][i * 16 + g * 4 + r][w] = sv[i * 4 + r];
        sred[1][i * 16 + g * 4 + r][w] = qv[i * 4 + r];
      }
  }
  __syncthreads();
  #pragma unroll
  for (int i = 0; i < 4; ++i) {
    #pragma unroll
    for (int r = 0; r < 4; ++r) {
      int lrow = i * 16 + g * 4 + r;
      float S = 0.0f, SS = 0.0f;
      #pragma unroll
      for (int ww = 0; ww < 8; ++ww) { S += sred[0][lrow][ww]; SS += sred[1][lrow][ww]; }
      float mu  = S * (1.0f / 1024.0f);
      float var = (SS - 1024.0f * mu * mu) * (1.0f / 1023.0f);
      var = var < 0.0f ? 0.0f : var;
      float rs = 1.0f / (sqrtf(var) + 1e-3f);
      float* orow = outp + (size_t)(m0 + lrow) * 8192 + nc0 + w * 128 + q16;
      #pragma unroll
      for (int n = 0; n < 8; ++n)
        orow[n * 16] = (acc[i][n][r] - mu) * rs * gav[n] + bev[n];
    }
  }
}

// ---------------------------------------------------------------------------
extern "C" void kernel_launch(void* const* d_in, const int* in_sizes, int n_in,
                              void* d_out, int out_size, void* d_ws, size_t ws_size,
                              hipStream_t stream) {
  const float* v     = (const float*)d_in[2];
  const float* wvs   = (const float*)d_in[5];
  const float* pw    = (const float*)d_in[6];
  const float* pb    = (const float*)d_in[7];
  const float* gamma = (const float*)d_in[8];
  const float* beta  = (const float*)d_in[9];
  float* out = (float*)d_out;

  // ws layout (bytes): PW bf16 16M | WvT bf16 2M | A2 bf16 8M
  const size_t OFF_WVT = 16777216;
  const size_t OFF_A2  = OFF_WVT + 2097152;

  bf16* PWb = (bf16*)d_ws;
  bf16* WvT = (bf16*)((char*)d_ws + OFF_WVT);
  bf16* A2  = (bf16*)((char*)d_ws + OFF_A2);

  hipLaunchKernelGGL(prep_pw_kernel,    dim3(8192), dim3(256), 0, stream, pw, PWb);
  hipLaunchKernelGGL(prep_wvt_kernel,   dim3(4096), dim3(256), 0, stream, wvs, WvT);
  hipLaunchKernelGGL(fill_attns_kernel, dim3(128),  dim3(256), 0, stream, out);
  hipLaunchKernelGGL(gemm1_kernel,  dim3(64, 8), dim3(256), 0, stream, v, WvT, A2);
  hipLaunchKernelGGL(gemm2ln_kernel, dim3(512),  dim3(512), 0, stream,
                     A2, PWb, v, pb, gamma, beta, out);
}

// Round 4
// 202.607 us; speedup vs baseline: 1.0513x; 1.0513x over previous
//
#include <hip/hip_runtime.h>
#include <cstdint>
#include <cstddef>

#define MB_   4096
#define NK_   8
#define DM_   1024
#define DT_   128

typedef __bf16 bf16;
typedef __bf16 bf16x8 __attribute__((ext_vector_type(8)));
typedef __bf16 bf16x4 __attribute__((ext_vector_type(4)));
typedef float  f32x4  __attribute__((ext_vector_type(4)));

__device__ __forceinline__ void gload_lds16(const void* g, void* l) {
  __builtin_amdgcn_global_load_lds(
      (__attribute__((address_space(1))) void*)g,
      (__attribute__((address_space(3))) void*)l,
      16, 0, 0);
}

__device__ __forceinline__ int hsw(int r) { return (r ^ (r >> 2)) & 3; }

// ---------------------------------------------------------------------------
// prep: proj_w f32 [8192][1024] -> bf16
__global__ void prep_pw_kernel(const float* __restrict__ pw, bf16* __restrict__ pwb) {
  size_t i = ((size_t)blockIdx.x * 256 + threadIdx.x) * 4;
  float4 f = *(const float4*)&pw[i];
  bf16x4 o = { (bf16)f.x, (bf16)f.y, (bf16)f.z, (bf16)f.w };
  *(bf16x4*)&pwb[i] = o;
}

// prep: w_vs [8][1024][128] f32 -> WvT [8][128][1024] bf16
__global__ void prep_wvt_kernel(const float* __restrict__ wvs, bf16* __restrict__ wvt) {
  int o = blockIdx.x * 256 + threadIdx.x;
  int d = o & 1023;
  int t = (o >> 10) & 127;
  int n = o >> 17;
  wvt[o] = (bf16)wvs[(size_t)n * 131072 + (size_t)d * 128 + t];
}

__global__ void fill_attns_kernel(float* __restrict__ out) {
  out[(size_t)33554432 + blockIdx.x * 256 + threadIdx.x] = 1.0f;
}

// ---------------------------------------------------------------------------
// GEMM1: v_s[n] = V_n[4096x1024](f32) @ WvT[n][128x1024]^T -> A2 scatter (bf16)
__global__ __launch_bounds__(256, 2) void gemm1_kernel(
    const float* __restrict__ vflat, const bf16* __restrict__ WvT,
    bf16* __restrict__ A2)
{
  __shared__ __align__(16) bf16 As[64 * 32];
  __shared__ __align__(16) bf16 Bs[128 * 32];
  const int tid  = threadIdx.x;
  const int wave = tid >> 6, lane = tid & 63;
  const int wm = wave >> 1, wn = wave & 1;
  const int n  = blockIdx.y;
  const int b0 = blockIdx.x * 64;

  const int r  = tid >> 2;
  const int hr = hsw(r);
  const int cs = (tid & 3) ^ hr;

  const float* ag = vflat + ((size_t)(n * MB_ + b0 + r)) * 1024 + (tid & 3) * 8;
  bf16* awr = As + r * 32 + cs * 8;
  const bf16* bg = WvT + (size_t)n * 131072 + (size_t)r * 1024 + cs * 8;
  char* bsb = (char*)Bs + wave * 1024;

  f32x4 acc[2][4] = {};
  const int krow = lane & 15;
  const int cch  = lane >> 4;
  const int swoff = ((cch ^ hsw(krow)) << 4);

  for (int kt = 0; kt < 32; ++kt) {
    const bf16* bptr = bg + kt * 32;
    gload_lds16(bptr,             bsb);
    gload_lds16(bptr + 64 * 1024, bsb + 4096);
    const float* aptr = ag + kt * 32;
    float4 f0 = *(const float4*)(aptr + 0);
    float4 f1 = *(const float4*)(aptr + 4);
    bf16x8 h0 = { (bf16)f0.x, (bf16)f0.y, (bf16)f0.z, (bf16)f0.w,
                  (bf16)f1.x, (bf16)f1.y, (bf16)f1.z, (bf16)f1.w };
    *(bf16x8*)awr = h0;
    __syncthreads();

    bf16x8 af[2], bfr[4];
    #pragma unroll
    for (int i = 0; i < 2; ++i)
      af[i] = *(const bf16x8*)((const char*)As + (wm * 32 + i * 16 + krow) * 64 + swoff);
    #pragma unroll
    for (int j = 0; j < 4; ++j)
      bfr[j] = *(const bf16x8*)((const char*)Bs + (wn * 64 + j * 16 + krow) * 64 + swoff);
    #pragma unroll
    for (int i = 0; i < 2; ++i)
      #pragma unroll
      for (int j = 0; j < 4; ++j)
        acc[i][j] = __builtin_amdgcn_mfma_f32_16x16x32_bf16(af[i], bfr[j], acc[i][j], 0, 0, 0);
    __syncthreads();
  }

  #pragma unroll
  for (int i = 0; i < 2; ++i) {
    #pragma unroll
    for (int j = 0; j < 4; ++j) {
      int t = wn * 64 + j * 16 + (lane & 15);
      #pragma unroll
      for (int rr = 0; rr < 4; ++rr) {
        int b = b0 + wm * 32 + i * 16 + (lane >> 4) * 4 + rr;
        size_t off = ((size_t)(n * 512 + (b >> 3))) * 1024 + (size_t)(b & 7) * 128 + t;
        A2[off] = (bf16)acc[i][j][rr];
      }
    }
  }
}

// ---------------------------------------------------------------------------
// GEMM2 pipelined: z[4096][8192] = A2 @ PW^T + pb. Tile 256x256, BK=32,
// 4 LDS buffers (tiles t..t+3 mod 4), counted vmcnt(4) per tile (T3+T4),
// setprio around MFMA (T5). 8 waves (2m x 4n), per-wave 128x64.
template<bool ZB>
__global__ __launch_bounds__(512, 2) void gemm2p_kernel(
    const bf16* __restrict__ A2, const bf16* __restrict__ PW,
    const float* __restrict__ pb, void* __restrict__ zoutp)
{
  __shared__ __align__(16) bf16 As[4][8192];  // [buf][256*32]
  __shared__ __align__(16) bf16 Bs[4][8192];

  const int tid  = threadIdx.x;
  const int w    = tid >> 6;
  const int lane = tid & 63;
  const int wm   = w >> 2;       // 0..1
  const int wn   = w & 3;        // 0..3

  // XCD-bijective swizzle: XCD x owns a contiguous 4-wide n strip.
  const int bid   = blockIdx.x;          // 0..511
  const int x     = bid & 7;
  const int local = bid >> 3;            // 0..63
  const int mt    = local & 15;
  const int nt    = x * 4 + (local >> 4);
  const int m0    = mt * 256;
  const int n0    = nt * 256;

  // staging addresses (per thread: 2 chunks per matrix per tile)
  const char* aG0 = (const char*)A2 + (size_t)(m0 + (tid >> 2)) * 2048 + (tid & 3) * 16;
  const char* aG1 = aG0 + (size_t)128 * 2048;
  const char* bG0 = (const char*)PW + (size_t)(n0 + (tid >> 2)) * 2048 + (tid & 3) * 16;
  const char* bG1 = bG0 + (size_t)128 * 2048;

  #define STAGE_A(t) { char* d = (char*)As[(t) & 3] + tid * 16;            \
                       gload_lds16(aG0 + (t) * 64, d);                      \
                       gload_lds16(aG1 + (t) * 64, d + 8192); }
  #define STAGE_B(t) { char* d = (char*)Bs[(t) & 3] + tid * 16;            \
                       gload_lds16(bG0 + (t) * 64, d);                      \
                       gload_lds16(bG1 + (t) * 64, d + 8192); }

  // prologue: tiles 0 and 1 (8 loads); wait until tile 0 landed (4 in flight)
  STAGE_A(0); STAGE_B(0); STAGE_A(1); STAGE_B(1);
  asm volatile("s_waitcnt vmcnt(4)" ::: "memory");
  __builtin_amdgcn_sched_barrier(0);
  __builtin_amdgcn_s_barrier();

  f32x4 acc[8][4] = {};
  const int fr = lane & 15;
  const int kc = (lane >> 4) * 8;
  const int aRd = (wm * 128 + fr) * 32 + kc;   // element offset in As[buf]
  const int bRd = (wn * 64  + fr) * 32 + kc;

  #pragma unroll 4
  for (int t = 0; t < 32; ++t) {
    const bf16* pA = &As[t & 3][aRd];
    const bf16* pB = &Bs[t & 3][bRd];

    // ---- phase 1: A m0-3 + B n0-3 reads, stage A(t+2), MFMA Q0 ----
    bf16x8 a[4], b[4];
    #pragma unroll
    for (int m = 0; m < 4; ++m) a[m] = *(const bf16x8*)(pA + m * 512);
    #pragma unroll
    for (int n = 0; n < 4; ++n) b[n] = *(const bf16x8*)(pB + n * 512);
    if (t < 30) STAGE_A(t + 2);
    __builtin_amdgcn_s_barrier();
    __builtin_amdgcn_s_setprio(1);
    #pragma unroll
    for (int m = 0; m < 4; ++m)
      #pragma unroll
      for (int n = 0; n < 4; ++n)
        acc[m][n] = __builtin_amdgcn_mfma_f32_16x16x32_bf16(a[m], b[n], acc[m][n], 0, 0, 0);
    __builtin_amdgcn_s_setprio(0);
    __builtin_amdgcn_s_barrier();

    // ---- phase 2: A m4-7 reads, stage B(t+2), counted vmcnt, MFMA Q1 ----
    bf16x8 a2[4];
    #pragma unroll
    for (int m = 0; m < 4; ++m) a2[m] = *(const bf16x8*)(pA + (4 + m) * 512);
    if (t < 30) STAGE_B(t + 2);
    __builtin_amdgcn_s_barrier();
    __builtin_amdgcn_s_setprio(1);
    #pragma unroll
    for (int m = 0; m < 4; ++m)
      #pragma unroll
      for (int n = 0; n < 4; ++n)
        acc[4 + m][n] = __builtin_amdgcn_mfma_f32_16x16x32_bf16(a2[m], b[n], acc[4 + m][n], 0, 0, 0);
    __builtin_amdgcn_s_setprio(0);
    // single counted wait per K-tile: tile t+1 must be fully landed
    if (t < 30)       { asm volatile("s_waitcnt vmcnt(4)" ::: "memory"); }
    else if (t == 30) { asm volatile("s_waitcnt vmcnt(0)" ::: "memory"); }
    __builtin_amdgcn_sched_barrier(0);
    __builtin_amdgcn_s_barrier();
  }
  #undef STAGE_A
  #undef STAGE_B

  // epilogue: z = acc + pb -> bf16 ws (or f32 d_out)
  #pragma unroll
  for (int m = 0; m < 8; ++m) {
    #pragma unroll
    for (int n = 0; n < 4; ++n) {
      int nn = n0 + wn * 64 + n * 16 + fr;
      float pbn = pb[nn];
      #pragma unroll
      for (int r = 0; r < 4; ++r) {
        int mm = m0 + wm * 128 + m * 16 + (lane >> 4) * 4 + r;
        size_t off = (size_t)mm * 8192 + nn;
        float val = acc[m][n][r] + pbn;
        if (ZB) ((bf16*)zoutp)[off] = (bf16)val;
        else    ((float*)zoutp)[off] = val;
      }
    }
  }
}

// ---------------------------------------------------------------------------
// LN over 1024-wide rows: x = z + v(residual); ddof=1, eps outside sqrt.
template<bool ZB>
__global__ __launch_bounds__(256) void ln_kernel(
    const void* zin, const float* __restrict__ vres,
    const float* __restrict__ gamma, const float* __restrict__ beta,
    float* outp)
{
  __shared__ float red[16];
  const int row = blockIdx.x;
  const int tid = threadIdx.x;
  const size_t base = (size_t)row * 1024 + tid * 4;

  float4 rv = *(const float4*)&vres[base];
  float4 x;
  if (ZB) {
    bf16x4 zb4 = *(const bf16x4*)((const bf16*)zin + base);
    x.x = (float)zb4[0] + rv.x; x.y = (float)zb4[1] + rv.y;
    x.z = (float)zb4[2] + rv.z; x.w = (float)zb4[3] + rv.w;
  } else {
    float4 zf = *(const float4*)((const float*)zin + base);
    x.x = zf.x + rv.x; x.y = zf.y + rv.y; x.z = zf.z + rv.z; x.w = zf.w + rv.w;
  }

  float s  = x.x + x.y + x.z + x.w;
  float ss = x.x * x.x + x.y * x.y + x.z * x.z + x.w * x.w;
  #pragma unroll
  for (int m = 32; m >= 1; m >>= 1) {
    s  += __shfl_xor(s,  m, 64);
    ss += __shfl_xor(ss, m, 64);
  }
  const int wave = tid >> 6, lane = tid & 63;
  if (lane == 0) { red[wave] = s; red[wave + 8] = ss; }
  __syncthreads();
  float S  = red[0] + red[1] + red[2] + red[3];
  float SS = red[8] + red[9] + red[10] + red[11];
  float mu  = S * (1.0f / 1024.0f);
  float var = (SS - 1024.0f * mu * mu) * (1.0f / 1023.0f);
  var = var < 0.0f ? 0.0f : var;
  float rs = 1.0f / (sqrtf(var) + 1e-3f);
  float4 g  = *(const float4*)&gamma[tid * 4];
  float4 be = *(const float4*)&beta[tid * 4];
  float4 y;
  y.x = (x.x - mu) * rs * g.x + be.x;
  y.y = (x.y - mu) * rs * g.y + be.y;
  y.z = (x.z - mu) * rs * g.z + be.z;
  y.w = (x.w - mu) * rs * g.w + be.w;
  *(float4*)&outp[base] = y;
}

// ---------------------------------------------------------------------------
extern "C" void kernel_launch(void* const* d_in, const int* in_sizes, int n_in,
                              void* d_out, int out_size, void* d_ws, size_t ws_size,
                              hipStream_t stream) {
  const float* v     = (const float*)d_in[2];
  const float* wvs   = (const float*)d_in[5];
  const float* pw    = (const float*)d_in[6];
  const float* pb    = (const float*)d_in[7];
  const float* gamma = (const float*)d_in[8];
  const float* beta  = (const float*)d_in[9];
  float* out = (float*)d_out;

  // ws layout (bytes): PW bf16 16M | WvT bf16 2M | A2 bf16 8M | zg bf16 64M
  const size_t OFF_WVT = 16777216;
  const size_t OFF_A2  = OFF_WVT + 2097152;
  const size_t OFF_ZG  = OFF_A2 + 8388608;
  const size_t NEED_ZB = OFF_ZG + 67108864;

  bf16* PWb = (bf16*)d_ws;
  bf16* WvT = (bf16*)((char*)d_ws + OFF_WVT);
  bf16* A2  = (bf16*)((char*)d_ws + OFF_A2);
  const bool zb = (ws_size >= NEED_ZB);
  void* zbuf = zb ? (void*)((char*)d_ws + OFF_ZG) : (void*)out;

  hipLaunchKernelGGL(prep_pw_kernel,    dim3(8192), dim3(256), 0, stream, pw, PWb);
  hipLaunchKernelGGL(prep_wvt_kernel,   dim3(4096), dim3(256), 0, stream, wvs, WvT);
  hipLaunchKernelGGL(fill_attns_kernel, dim3(128),  dim3(256), 0, stream, out);
  hipLaunchKernelGGL(gemm1_kernel, dim3(64, 8), dim3(256), 0, stream, v, WvT, A2);
  if (zb) {
    hipLaunchKernelGGL((gemm2p_kernel<true>),  dim3(512), dim3(512), 0, stream, A2, PWb, pb, zbuf);
    hipLaunchKernelGGL((ln_kernel<true>),      dim3(32768), dim3(256), 0, stream, zbuf, v, gamma, beta, out);
  } else {
    hipLaunchKernelGGL((gemm2p_kernel<false>), dim3(512), dim3(512), 0, stream, A2, PWb, pb, zbuf);
    hipLaunchKernelGGL((ln_kernel<false>),     dim3(32768), dim3(256), 0, stream, zbuf, v, gamma, beta, out);
  }
}